// Round 7
// baseline (508.893 us; speedup 1.0000x reference)
//
#include <hip/hip_runtime.h>
#include <hip/hip_bf16.h>

typedef __attribute__((ext_vector_type(8))) short bf16x8;
typedef __attribute__((ext_vector_type(4))) float f32x4;
typedef unsigned short u16;

constexpr int NSEQ = 16384;
constexpr int KD   = 4096;
constexpr int NQ   = 512;     // q cols
constexpr int NCOL = 640;     // q (512) + k (128)
constexpr int BM   = 128;
constexpr int BK   = 32;
constexpr int KHALF = 2048;
constexpr int NKS  = KHALF / BK;                     // 64 K-steps per block
constexpr int CHUNKS_PER_TILE = NCOL * BK * 2 / 16;  // 2560 chunks of 16B
constexpr int NTILES = KD / BK;                      // 128
constexpr int TOTAL_CHUNKS = CHUNKS_PER_TILE * NTILES;
constexpr int TILE_U16 = CHUNKS_PER_TILE * 8;        // 20480 u16 per tile
constexpr int B_BYTES  = 40960;
constexpr int BUF_BYTES = 49152;                     // 40KB B + 8KB A

// ---- f32 -> bf16 (RTNE) pack helpers -------------------------------------
__device__ __forceinline__ unsigned bf_round(float x) {
    unsigned u = __builtin_bit_cast(unsigned, x);
    unsigned r = u + 0x7FFFu + ((u >> 16) & 1u);
    return r >> 16;
}
__device__ __forceinline__ unsigned pk2(float lo, float hi) {
    return bf_round(lo) | (bf_round(hi) << 16);
}
__device__ __forceinline__ float bfu(unsigned u) {
    return __builtin_bit_cast(float, u << 16);
}

// ---- Kernel 1: convert W (q_w ++ k_w) f32 -> bf16, pre-swizzled chunks ----
__global__ __launch_bounds__(256) void wconv_kernel(
    const float* __restrict__ qw, const float* __restrict__ kw,
    u16* __restrict__ Wst)
{
    int cg = blockIdx.x * 256 + threadIdx.x;
    int kk = cg / CHUNKS_PER_TILE;
    int c  = cg - kk * CHUNKS_PER_TILE;
    int n  = c >> 2;
    int s  = c & 3;
    int k0 = kk * BK + ((s ^ ((n >> 1) & 3)) << 3);
    const float* src = (n < NQ) ? (qw + (size_t)n * KD + k0)
                                : (kw + (size_t)(n - NQ) * KD + k0);
    float4 v0 = *(const float4*)(src);
    float4 v1 = *(const float4*)(src + 4);
    int4 o;
    o.x = (int)pk2(v0.x, v0.y);
    o.y = (int)pk2(v0.z, v0.w);
    o.z = (int)pk2(v1.x, v1.y);
    o.w = (int)pk2(v1.z, v1.w);
    *(int4*)(Wst + (size_t)cg * 8) = o;
}

// ---- Kernel 2: K-split GEMM — ABLATION TEMPLATE --------------------------
// MODE 0: full (correct, runs last).  MODE 1: stage-only.  MODE 2:
// compute-only.  MODE 3: MFMA-only + barrier skeleton.  MODE 4: MFMA-only.
template<int MODE>
__global__ __launch_bounds__(512, 2) void gemm_kernel(
    const float* __restrict__ hid, const u16* __restrict__ Wst,
    u16* __restrict__ P0, u16* __restrict__ P1)
{
    constexpr bool kStage   = (MODE == 0 || MODE == 1);
    constexpr bool kCompute = (MODE == 0 || MODE == 2);

    __shared__ __align__(16) char smem[2 * BUF_BYTES];   // 96 KB

    const int t    = threadIdx.x;
    const int lane = t & 63;
    const int wid  = t >> 6;
    const int wm   = wid >> 2;
    const int wq   = wid & 3;

    const int b    = blockIdx.x;
    const int xcd  = b & 7;
    const int kh   = xcd & 1;
    const int mblk = (b >> 3) * 4 + (xcd >> 1);   // 0..127, bijective
    const int row0 = mblk * BM;

    const float* hk   = hid + (size_t)row0 * KD + kh * KHALF;
    const u16*  wbase = Wst + (size_t)(kh * NKS) * TILE_U16;
    u16* P = kh ? P1 : P0;

    f32x4 acc[4][10] = {};

    const int ar  = t >> 2;
    const int ks8 = t & 3;
    const float* gA = hk + (size_t)ar * KD + ks8 * 8;
    const int aWoff = ar * 64 + ((ks8 ^ ((ar >> 1) & 3)) << 4);

    const int bn    = lane & 15;
    const int kslot = lane >> 4;
    const int koff  = (kslot ^ ((bn >> 1) & 3)) << 4;

    float4 s0a, s0b, s1a, s1b;

#define GL(IT, TP, SBN)                                                          \
    __builtin_amdgcn_global_load_lds(                                            \
        (const __attribute__((address_space(1))) void*)((TP) + (size_t)((IT) * 512 + t) * 8), \
        (__attribute__((address_space(3))) void*)((SBN) + wid * 1024 + (IT) * 8192), \
        16, 0, 0)

#define BAR1()                                                                   \
    __builtin_amdgcn_s_barrier();                                                \
    asm volatile("s_waitcnt lgkmcnt(0)" ::: "memory");                           \
    __builtin_amdgcn_sched_barrier(0);                                           \
    __builtin_amdgcn_s_setprio(1)

#define ENDP()                                                                   \
    __builtin_amdgcn_sched_barrier(0);                                           \
    __builtin_amdgcn_s_setprio(0);                                               \
    __builtin_amdgcn_s_barrier()

#define RDA(M) (*(const bf16x8*)(sAc + (wm * 64 + (M) * 16 + bn) * 64 + koff))
#define RDB(F) (*(const bf16x8*)(sBc + (wq * 160 + (F) * 16 + bn) * 64 + koff))

#define MF(F, B)                                                                 \
    acc[0][F] = __builtin_amdgcn_mfma_f32_16x16x32_bf16(af0, B, acc[0][F], 0, 0, 0); \
    acc[1][F] = __builtin_amdgcn_mfma_f32_16x16x32_bf16(af1, B, acc[1][F], 0, 0, 0); \
    acc[2][F] = __builtin_amdgcn_mfma_f32_16x16x32_bf16(af2, B, acc[2][F], 0, 0, 0); \
    acc[3][F] = __builtin_amdgcn_mfma_f32_16x16x32_bf16(af3, B, acc[3][F], 0, 0, 0)

    // ---- common prologue: A(0); glds(0)->buf0; A(1); ds_write A(0); drain ----
    s0a = *(const float4*)(gA);
    s0b = *(const float4*)(gA + 4);
    {
        const u16* tp = wbase;
        GL(0, tp, smem); GL(1, tp, smem); GL(2, tp, smem); GL(3, tp, smem); GL(4, tp, smem);
    }
    s1a = *(const float4*)(gA + BK);
    s1b = *(const float4*)(gA + BK + 4);
    {
        int4 ap_;
        ap_.x = (int)pk2(s0a.x, s0a.y);  ap_.y = (int)pk2(s0a.z, s0a.w);
        ap_.z = (int)pk2(s0b.x, s0b.y);  ap_.w = (int)pk2(s0b.z, s0b.w);
        *(int4*)(smem + B_BYTES + aWoff) = ap_;
    }
    asm volatile("s_waitcnt vmcnt(0) lgkmcnt(0)" ::: "memory");
    __builtin_amdgcn_s_barrier();

    if constexpr (MODE >= 3) {
        // ---- MFMA-only paths: frags read once, reused 64 steps ----
        char* sBc = smem;
        char* sAc = smem + B_BYTES;
        bf16x8 af0 = RDA(0), af1 = RDA(1), af2 = RDA(2), af3 = RDA(3);
        bf16x8 bb0 = RDB(0), bb1 = RDB(1), bb2 = RDB(2), bb3 = RDB(3), bb4 = RDB(4);
        bf16x8 bb5 = RDB(5), bb6 = RDB(6), bb7 = RDB(7), bb8 = RDB(8), bb9 = RDB(9);
        asm volatile("s_waitcnt lgkmcnt(0)" ::: "memory");
#pragma unroll 1
        for (int s = 0; s < NKS; ++s) {
            if constexpr (MODE == 3) {
                BAR1(); MF(0, bb0); MF(1, bb1); ENDP();
                BAR1(); MF(2, bb2); MF(3, bb3); MF(4, bb4); ENDP();
                BAR1(); MF(5, bb5); MF(6, bb6); MF(7, bb7); ENDP();
                BAR1(); MF(8, bb8); MF(9, bb9); ENDP();
            } else {
                MF(0, bb0); MF(1, bb1); MF(2, bb2); MF(3, bb3); MF(4, bb4);
                MF(5, bb5); MF(6, bb6); MF(7, bb7); MF(8, bb8); MF(9, bb9);
            }
        }
    } else {

#define STEP(TT, CUR, SWa, SWb, SLa, SLb, HG, HA)                                \
    {                                                                            \
        char* sBc = smem + (CUR) * BUF_BYTES;                                    \
        char* sAc = sBc + B_BYTES;                                               \
        char* sBn = smem + ((CUR) ^ 1) * BUF_BYTES;                              \
        const u16* tp = wbase + (size_t)((TT) + 1) * TILE_U16;                   \
        (void)sAc; (void)sBn; (void)tp;                                          \
        /* ---- P1 ---- */                                                       \
        {                                                                        \
            bf16x8 af0{}, af1{}, af2{}, af3{}, b0{}, b1{};                       \
            if constexpr (kCompute) {                                            \
                af0 = RDA(0); af1 = RDA(1); af2 = RDA(2); af3 = RDA(3);          \
                b0 = RDB(0); b1 = RDB(1);                                        \
            }                                                                    \
            if (kStage && (HA)) { SLa = *(const float4*)(gA + ((TT) + 2) * BK);  \
                      SLb = *(const float4*)(gA + ((TT) + 2) * BK + 4); }        \
            if (kStage && (HG)) { GL(0, tp, sBn); GL(1, tp, sBn); }              \
            BAR1();                                                              \
            if constexpr (kCompute) { MF(0, b0); MF(1, b1); }                    \
            ENDP();                                                              \
            /* ---- P2 ---- */                                                   \
            if constexpr (kCompute) { b0 = RDB(2); b1 = RDB(3); }                \
            bf16x8 b2{};                                                         \
            if constexpr (kCompute) { b2 = RDB(4); }                             \
            if (kStage && (HG)) {                                                \
                int4 ap_;                                                        \
                ap_.x = (int)pk2(SWa.x, SWa.y);  ap_.y = (int)pk2(SWa.z, SWa.w); \
                ap_.z = (int)pk2(SWb.x, SWb.y);  ap_.w = (int)pk2(SWb.z, SWb.w); \
                *(int4*)(sBn + B_BYTES + aWoff) = ap_;                           \
                GL(2, tp, sBn); GL(3, tp, sBn);                                  \
            }                                                                    \
            BAR1();                                                              \
            if constexpr (kCompute) { MF(2, b0); MF(3, b1); MF(4, b2); }         \
            ENDP();                                                              \
            /* ---- P3 ---- */                                                   \
            if constexpr (kCompute) { b0 = RDB(5); b1 = RDB(6); b2 = RDB(7); }   \
            if (kStage && (HG)) GL(4, tp, sBn);                                  \
            BAR1();                                                              \
            if constexpr (kCompute) { MF(5, b0); MF(6, b1); MF(7, b2); }         \
            ENDP();                                                              \
            /* ---- P4 ---- */                                                   \
            if constexpr (kCompute) { b0 = RDB(8); b1 = RDB(9); }                \
            BAR1();                                                              \
            if constexpr (kCompute) { MF(8, b0); MF(9, b1); }                    \
            __builtin_amdgcn_sched_barrier(0);                                   \
            __builtin_amdgcn_s_setprio(0);                                       \
            if (kStage && (HG)) { asm volatile("s_waitcnt vmcnt(0)" ::: "memory"); } \
            __builtin_amdgcn_s_barrier();                                        \
        }                                                                        \
    }

        // ---- steady: tt = 0..61 ----
#pragma unroll 1
        for (int t2 = 0; t2 < 31; ++t2) {
            const int tt = t2 * 2;
            STEP(tt,     0, s1a, s1b, s0a, s0b, 1, 1)
            STEP(tt + 1, 1, s0a, s0b, s1a, s1b, 1, 1)
        }
        // ---- tail ----
        STEP(62, 0, s1a, s1b, s0a, s0b, 1, 0)
        STEP(63, 1, s0a, s0b, s1a, s1b, 0, 0)
#undef STEP
    }

#undef GL
#undef BAR1
#undef ENDP
#undef RDA
#undef RDB
#undef MF

    // epilogue: bf16 P write (all modes — keeps acc live; M0 runs last)
    const int crow = (lane >> 4) << 2;
    const int ccol = lane & 15;
    u16* Pp = P + (size_t)(row0 + wm * 64) * NCOL + wq * 160 + ccol;
    #pragma unroll
    for (int m = 0; m < 4; ++m)
        #pragma unroll
        for (int f = 0; f < 10; ++f)
            #pragma unroll
            for (int j = 0; j < 4; ++j)
                Pp[(size_t)(m * 16 + crow + j) * NCOL + f * 16] =
                    (u16)bf_round(acc[m][f][j]);
}

// ---- Kernel 3: gating epilogue (reads two bf16 partial-P halves) ----------
__global__ __launch_bounds__(256) void gate_kernel(
    const u16* __restrict__ P0, const u16* __restrict__ P1,
    const float* __restrict__ qb,
    const float* __restrict__ qnw, const float* __restrict__ knw,
    const float* __restrict__ kbase, const float* __restrict__ bb,
    float* __restrict__ out)
{
    __shared__ float skb[8 * 16 * 16];
    __shared__ float sqb[512];
    __shared__ float sb[32];
    __shared__ float snw[32];

    int tid = threadIdx.x;
    for (int i = tid; i < 2048; i += 256) skb[i] = kbase[i];
    for (int i = tid; i < 512;  i += 256) sqb[i] = qb[i];
    if (tid < 32) sb[tid] = bb[tid];
    if (tid < 16) snw[tid] = qnw[tid];
    else if (tid < 32) snw[tid] = knw[tid - 16];
    __syncthreads();

    int gid = blockIdx.x * 256 + tid;
    int tok = gid >> 5;
    int hh  = (gid >> 2) & 7;
    int g   = gid & 3;

    const u16* r0 = P0 + (size_t)tok * NCOL;
    const u16* r1 = P1 + (size_t)tok * NCOL;
    const int qoff = (hh * 4 + g) * 16;

    float q[16];
    float ss = 0.f;
    {
        int4 a0 = *(const int4*)(r0 + qoff);
        int4 a1 = *(const int4*)(r0 + qoff + 8);
        int4 b0 = *(const int4*)(r1 + qoff);
        int4 b1 = *(const int4*)(r1 + qoff + 8);
        int wa[8] = {a0.x, a0.y, a0.z, a0.w, a1.x, a1.y, a1.z, a1.w};
        int wb[8] = {b0.x, b0.y, b0.z, b0.w, b1.x, b1.y, b1.z, b1.w};
        #pragma unroll
        for (int i = 0; i < 8; ++i) {
            unsigned ua = (unsigned)wa[i], ub = (unsigned)wb[i];
            q[2*i+0] = bfu(ua & 0xFFFFu) + bfu(ub & 0xFFFFu) + sqb[qoff + 2*i+0];
            q[2*i+1] = bfu(ua >> 16)     + bfu(ub >> 16)     + sqb[qoff + 2*i+1];
        }
        #pragma unroll
        for (int d = 0; d < 16; ++d) ss += q[d] * q[d];
    }
    float rq = rsqrtf(ss * (1.f / 16.f) + 1e-6f);
    #pragma unroll
    for (int d = 0; d < 16; ++d) q[d] *= rq * snw[d];

    float k[16];
    float sk = 0.f;
    {
        const int koffb = NQ + hh * 16;
        int4 a0 = *(const int4*)(r0 + koffb);
        int4 a1 = *(const int4*)(r0 + koffb + 8);
        int4 b0 = *(const int4*)(r1 + koffb);
        int4 b1 = *(const int4*)(r1 + koffb + 8);
        int wa[8] = {a0.x, a0.y, a0.z, a0.w, a1.x, a1.y, a1.z, a1.w};
        int wb[8] = {b0.x, b0.y, b0.z, b0.w, b1.x, b1.y, b1.z, b1.w};
        #pragma unroll
        for (int i = 0; i < 8; ++i) {
            unsigned ua = (unsigned)wa[i], ub = (unsigned)wb[i];
            k[2*i+0] = bfu(ua & 0xFFFFu) + bfu(ub & 0xFFFFu);
            k[2*i+1] = bfu(ua >> 16)     + bfu(ub >> 16);
        }
        #pragma unroll
        for (int d = 0; d < 16; ++d) sk += k[d] * k[d];
    }
    float rk = rsqrtf(sk * (1.f / 16.f) + 1e-6f);

    float logit = 0.f;
    #pragma unroll
    for (int d = 0; d < 16; ++d) logit += (k[d] * rk * snw[16 + d]) * q[d];
    logit = logit * 0.25f + sb[hh * 4 + g];

    float accum = 0.f;
    const float* kbh = skb + hh * 256;
    #pragma unroll
    for (int s = 0; s < 16; ++s) {
        float lb = 0.f;
        #pragma unroll
        for (int d = 0; d < 16; ++d) lb += kbh[s * 16 + d] * q[d];
        accum += __expf(lb * 0.25f - logit);
    }
    float r = 1.f / (1.f + accum);

    r += __shfl_xor(r, 1);
    r += __shfl_xor(r, 2);
    if (g == 0) out[(size_t)hh * NSEQ + tok] = r * 0.25f;
}

// ---- launch ---------------------------------------------------------------
extern "C" void kernel_launch(void* const* d_in, const int* in_sizes, int n_in,
                              void* d_out, int out_size, void* d_ws, size_t ws_size,
                              hipStream_t stream)
{
    const float* hid = (const float*)d_in[0];
    const float* qw  = (const float*)d_in[1];
    const float* qb  = (const float*)d_in[2];
    const float* kw  = (const float*)d_in[3];
    const float* qnw = (const float*)d_in[4];
    const float* knw = (const float*)d_in[5];
    const float* kb  = (const float*)d_in[6];
    const float* bb  = (const float*)d_in[7];
    float* out = (float*)d_out;

    u16* Wst = (u16*)d_ws;                                        // 5,242,880 B
    u16* P0  = (u16*)((char*)d_ws + (size_t)NCOL * KD * 2);       // 20,971,520 B
    u16* P1  = P0 + (size_t)NSEQ * NCOL;                          // 20,971,520 B

    wconv_kernel<<<TOTAL_CHUNKS / 256, 256, 0, stream>>>(qw, kw, Wst);
    // ---- ablation dispatches (outputs overwritten by the MODE 0 run) ----
    gemm_kernel<1><<<256, 512, 0, stream>>>(hid, Wst, P0, P1);  // stage-only
    gemm_kernel<2><<<256, 512, 0, stream>>>(hid, Wst, P0, P1);  // compute-only
    gemm_kernel<3><<<256, 512, 0, stream>>>(hid, Wst, P0, P1);  // MFMA+barriers
    gemm_kernel<4><<<256, 512, 0, stream>>>(hid, Wst, P0, P1);  // MFMA floor
    // ---- real run ----
    gemm_kernel<0><<<256, 512, 0, stream>>>(hid, Wst, P0, P1);
    gate_kernel<<<NSEQ * 32 / 256, 256, 0, stream>>>(P0, P1, qb, qnw, knw, kb, bb, out);
}

// Round 8
// 154.002 us; speedup vs baseline: 3.3045x; 3.3045x over previous
//
#include <hip/hip_runtime.h>
#include <hip/hip_bf16.h>

typedef __attribute__((ext_vector_type(8))) short bf16x8;
typedef __attribute__((ext_vector_type(4))) float f32x4;
typedef unsigned short u16;

constexpr int NSEQ = 16384;
constexpr int KD   = 4096;
constexpr int NQ   = 512;     // q cols
constexpr int NCOL = 640;     // q (512) + k (128)
constexpr int BM   = 128;
constexpr int BK   = 32;
constexpr int KHALF = 2048;
constexpr int NKS  = KHALF / BK;          // 64 K-steps per block
// Wst layout: [kh(2)][tt(64)][nblk(8)][frag i(5)][lane(64)][e(8)] u16
constexpr int WST_PER_KH = 64 * 8 * 5 * 64 * 8;   // 1,310,720 u16
constexpr int WST_TT     = 8 * 5 * 64 * 8;        // 20480 u16
constexpr int WST_NB     = 5 * 64 * 8;            // 2560 u16
constexpr int WCONV_THREADS = 2 * 64 * 8 * 5 * 64;   // 327,680

// ---- f32 -> bf16 (RTNE) pack helpers -------------------------------------
__device__ __forceinline__ unsigned bf_round(float x) {
    unsigned u = __builtin_bit_cast(unsigned, x);
    unsigned r = u + 0x7FFFu + ((u >> 16) & 1u);
    return r >> 16;
}
__device__ __forceinline__ unsigned pk2(float lo, float hi) {
    return bf_round(lo) | (bf_round(hi) << 16);
}
__device__ __forceinline__ float bfu(unsigned u) {
    return __builtin_bit_cast(float, u << 16);
}

// ---- Kernel 1: W (q_w ++ k_w) f32 -> bf16, per-(step,wave) fragment blocks
// Thread g -> frag: lane=g&63, i=(g>>6)%5, nblk, tt, kh.
// Holds W[n = nblk*80 + i*16 + (lane&15)][k = kh*2048 + tt*32 + (lane>>4)*8 .. +8]
// = exactly one MFMA B-fragment bf16x8; gemm wave wid=nblk loads frag i of
// step tt as ONE coalesced 1024B wave-load at Wst + idx*8.
__global__ __launch_bounds__(256) void wconv_kernel(
    const float* __restrict__ qw, const float* __restrict__ kw,
    u16* __restrict__ Wst)
{
    int g = blockIdx.x * 256 + threadIdx.x;
    int lane = g & 63;
    int r  = g >> 6;
    int i  = r % 5;  r /= 5;
    int nblk = r & 7;  r >>= 3;
    int tt = r & 63;
    int kh = r >> 6;
    int n  = nblk * 80 + i * 16 + (lane & 15);
    int k0 = kh * KHALF + tt * BK + ((lane >> 4) << 3);
    const float* src = (n < NQ) ? (qw + (size_t)n * KD + k0)
                                : (kw + (size_t)(n - NQ) * KD + k0);
    float4 v0 = *(const float4*)(src);
    float4 v1 = *(const float4*)(src + 4);
    int4 o;
    o.x = (int)pk2(v0.x, v0.y);
    o.y = (int)pk2(v0.z, v0.w);
    o.z = (int)pk2(v1.x, v1.y);
    o.w = (int)pk2(v1.z, v1.w);
    *(int4*)(Wst + (size_t)g * 8) = o;
}

// ---- Kernel 2: K-split GEMM, B streamed global->reg, A via tiny LDS dbuf --
// grid 256; XCD b&7 owns K-half (b&7)&1. 8 waves = 8 N-slices of 80 cols;
// wave tile 128 x 80, acc[8][5] f32x4. Per K-step: 5 plain B-frag loads
// (VGPR, compiler-pipelined vs 40 MFMA), A(t+1) ds_write to 8KB dbuf,
// A(t+2) reg prefetch, one lgkmcnt(0)+raw barrier. No glds, no manual vmcnt.
__global__ __launch_bounds__(512, 2) void gemm_kernel(
    const float* __restrict__ hid, const u16* __restrict__ Wst,
    u16* __restrict__ P0, u16* __restrict__ P1)
{
    __shared__ __align__(16) char smem[2 * 8192];   // A double-buffer only

    const int t    = threadIdx.x;
    const int lane = t & 63;
    const int wid  = t >> 6;        // 0..7 = N-slice

    const int b    = blockIdx.x;
    const int xcd  = b & 7;
    const int kh   = xcd & 1;
    const int mblk = (b >> 3) * 4 + (xcd >> 1);   // 0..127, bijective
    const int row0 = mblk * BM;

    const float* hk = hid + (size_t)row0 * KD + kh * KHALF;
    const u16*   wb = Wst + (size_t)kh * WST_PER_KH + wid * WST_NB + lane * 8;
    u16* P = kh ? P1 : P0;

    f32x4 acc[8][5] = {};

    // A staging: thread t -> row ar (0..127), k-slot ks8 (0..3), 8 f32
    const int ar  = t >> 2;
    const int ks8 = t & 3;
    const float* gA = hk + (size_t)ar * KD + ks8 * 8;
    const int aWoff = ar * 64 + ((ks8 ^ ((ar >> 1) & 3)) << 4);

    // A fragment read params (XOR-swizzled k-slot, 0-conflict proven R3/R6)
    const int bn   = lane & 15;
    const int koff = (((lane >> 4) ^ ((bn >> 1) & 3)) << 4);

    float4 s0a, s0b, s1a, s1b;

#define STEPX(TT, CUR, SWa, SWb, SLa, SLb, HG, HA)                               \
    {                                                                            \
        const u16* wp = wb + (size_t)(TT) * WST_TT;                              \
        bf16x8 bf0 = *(const bf16x8*)(wp);                                       \
        bf16x8 bf1 = *(const bf16x8*)(wp + 512);                                 \
        bf16x8 bf2 = *(const bf16x8*)(wp + 1024);                                \
        bf16x8 bf3 = *(const bf16x8*)(wp + 1536);                                \
        bf16x8 bf4 = *(const bf16x8*)(wp + 2048);                                \
        if (HA) { SLa = *(const float4*)(gA + ((TT) + 2) * BK);                  \
                  SLb = *(const float4*)(gA + ((TT) + 2) * BK + 4); }            \
        if (HG) {                                                                \
            int4 ap_;                                                            \
            ap_.x = (int)pk2(SWa.x, SWa.y);  ap_.y = (int)pk2(SWa.z, SWa.w);     \
            ap_.z = (int)pk2(SWb.x, SWb.y);  ap_.w = (int)pk2(SWb.z, SWb.w);     \
            *(int4*)(smem + ((CUR) ^ 1) * 8192 + aWoff) = ap_;                   \
        }                                                                        \
        const char* sAc = smem + (CUR) * 8192;                                   \
        _Pragma("unroll")                                                        \
        for (int m = 0; m < 8; ++m) {                                            \
            bf16x8 a_ = *(const bf16x8*)(sAc + (m * 16 + bn) * 64 + koff);       \
            acc[m][0] = __builtin_amdgcn_mfma_f32_16x16x32_bf16(a_, bf0, acc[m][0], 0, 0, 0); \
            acc[m][1] = __builtin_amdgcn_mfma_f32_16x16x32_bf16(a_, bf1, acc[m][1], 0, 0, 0); \
            acc[m][2] = __builtin_amdgcn_mfma_f32_16x16x32_bf16(a_, bf2, acc[m][2], 0, 0, 0); \
            acc[m][3] = __builtin_amdgcn_mfma_f32_16x16x32_bf16(a_, bf3, acc[m][3], 0, 0, 0); \
            acc[m][4] = __builtin_amdgcn_mfma_f32_16x16x32_bf16(a_, bf4, acc[m][4], 0, 0, 0); \
        }                                                                        \
        asm volatile("s_waitcnt lgkmcnt(0)" ::: "memory");                       \
        __builtin_amdgcn_s_barrier();                                            \
    }

    // ---- prologue: A(0),A(1) -> regs; ds_write A(0) -> buf0; barrier ----
    s0a = *(const float4*)(gA);
    s0b = *(const float4*)(gA + 4);
    s1a = *(const float4*)(gA + BK);
    s1b = *(const float4*)(gA + BK + 4);
    {
        int4 ap_;
        ap_.x = (int)pk2(s0a.x, s0a.y);  ap_.y = (int)pk2(s0a.z, s0a.w);
        ap_.z = (int)pk2(s0b.x, s0b.y);  ap_.w = (int)pk2(s0b.z, s0b.w);
        *(int4*)(smem + aWoff) = ap_;
    }
    asm volatile("s_waitcnt lgkmcnt(0)" ::: "memory");
    __builtin_amdgcn_s_barrier();

    // ---- steady: tt = 0..61 (rotation: even step writes s1, loads s0) ----
#pragma unroll 1
    for (int t2 = 0; t2 < 31; ++t2) {
        const int tt = t2 * 2;
        STEPX(tt,     0, s1a, s1b, s0a, s0b, 1, 1)
        STEPX(tt + 1, 1, s0a, s0b, s1a, s1b, 1, 1)
    }
    // ---- tail ----
    STEPX(62, 0, s1a, s1b, s0a, s0b, 1, 0)   // write A(63); no prefetch
    STEPX(63, 1, s0a, s0b, s1a, s1b, 0, 0)   // pure compute
#undef STEPX

    // epilogue: bf16 partial-P write. C/D: col=lane&15, row=(lane>>4)*4+j
    const int crow = (lane >> 4) << 2;
    const int ccol = lane & 15;
    #pragma unroll
    for (int m = 0; m < 8; ++m)
        #pragma unroll
        for (int f = 0; f < 5; ++f)
            #pragma unroll
            for (int j = 0; j < 4; ++j)
                P[(size_t)(row0 + m * 16 + crow + j) * NCOL
                  + wid * 80 + f * 16 + ccol] = (u16)bf_round(acc[m][f][j]);
}

// ---- Kernel 3: gating epilogue (reads two bf16 partial-P halves) ----------
__global__ __launch_bounds__(256) void gate_kernel(
    const u16* __restrict__ P0, const u16* __restrict__ P1,
    const float* __restrict__ qb,
    const float* __restrict__ qnw, const float* __restrict__ knw,
    const float* __restrict__ kbase, const float* __restrict__ bb,
    float* __restrict__ out)
{
    __shared__ float skb[8 * 16 * 16];
    __shared__ float sqb[512];
    __shared__ float sb[32];
    __shared__ float snw[32];

    int tid = threadIdx.x;
    for (int i = tid; i < 2048; i += 256) skb[i] = kbase[i];
    for (int i = tid; i < 512;  i += 256) sqb[i] = qb[i];
    if (tid < 32) sb[tid] = bb[tid];
    if (tid < 16) snw[tid] = qnw[tid];
    else if (tid < 32) snw[tid] = knw[tid - 16];
    __syncthreads();

    int gid = blockIdx.x * 256 + tid;
    int tok = gid >> 5;
    int hh  = (gid >> 2) & 7;
    int g   = gid & 3;

    const u16* r0 = P0 + (size_t)tok * NCOL;
    const u16* r1 = P1 + (size_t)tok * NCOL;
    const int qoff = (hh * 4 + g) * 16;

    // q row = P0 + P1 + bias, then RMSNorm
    float q[16];
    float ss = 0.f;
    {
        int4 a0 = *(const int4*)(r0 + qoff);
        int4 a1 = *(const int4*)(r0 + qoff + 8);
        int4 b0 = *(const int4*)(r1 + qoff);
        int4 b1 = *(const int4*)(r1 + qoff + 8);
        int wa[8] = {a0.x, a0.y, a0.z, a0.w, a1.x, a1.y, a1.z, a1.w};
        int wb[8] = {b0.x, b0.y, b0.z, b0.w, b1.x, b1.y, b1.z, b1.w};
        #pragma unroll
        for (int i = 0; i < 8; ++i) {
            unsigned ua = (unsigned)wa[i], ub = (unsigned)wb[i];
            q[2*i+0] = bfu(ua & 0xFFFFu) + bfu(ub & 0xFFFFu) + sqb[qoff + 2*i+0];
            q[2*i+1] = bfu(ua >> 16)     + bfu(ub >> 16)     + sqb[qoff + 2*i+1];
        }
        #pragma unroll
        for (int d = 0; d < 16; ++d) ss += q[d] * q[d];
    }
    float rq = rsqrtf(ss * (1.f / 16.f) + 1e-6f);
    #pragma unroll
    for (int d = 0; d < 16; ++d) q[d] *= rq * snw[d];

    // k row, RMSNorm
    float k[16];
    float sk = 0.f;
    {
        const int koffb = NQ + hh * 16;
        int4 a0 = *(const int4*)(r0 + koffb);
        int4 a1 = *(const int4*)(r0 + koffb + 8);
        int4 b0 = *(const int4*)(r1 + koffb);
        int4 b1 = *(const int4*)(r1 + koffb + 8);
        int wa[8] = {a0.x, a0.y, a0.z, a0.w, a1.x, a1.y, a1.z, a1.w};
        int wb[8] = {b0.x, b0.y, b0.z, b0.w, b1.x, b1.y, b1.z, b1.w};
        #pragma unroll
        for (int i = 0; i < 8; ++i) {
            unsigned ua = (unsigned)wa[i], ub = (unsigned)wb[i];
            k[2*i+0] = bfu(ua & 0xFFFFu) + bfu(ub & 0xFFFFu);
            k[2*i+1] = bfu(ua >> 16)     + bfu(ub >> 16);
        }
        #pragma unroll
        for (int d = 0; d < 16; ++d) sk += k[d] * k[d];
    }
    float rk = rsqrtf(sk * (1.f / 16.f) + 1e-6f);

    // logit = k̂·q̂ / 4 + b
    float logit = 0.f;
    #pragma unroll
    for (int d = 0; d < 16; ++d) logit += (k[d] * rk * snw[16 + d]) * q[d];
    logit = logit * 0.25f + sb[hh * 4 + g];

    // sum over sink tokens
    float accum = 0.f;
    const float* kbh = skb + hh * 256;
    #pragma unroll
    for (int s = 0; s < 16; ++s) {
        float lb = 0.f;
        #pragma unroll
        for (int d = 0; d < 16; ++d) lb += kbh[s * 16 + d] * q[d];
        accum += __expf(lb * 0.25f - logit);
    }
    float r = 1.f / (1.f + accum);

    // mean over g (4 lanes), lane g==0 writes
    r += __shfl_xor(r, 1);
    r += __shfl_xor(r, 2);
    if (g == 0) out[(size_t)hh * NSEQ + tok] = r * 0.25f;
}

// ---- launch ---------------------------------------------------------------
extern "C" void kernel_launch(void* const* d_in, const int* in_sizes, int n_in,
                              void* d_out, int out_size, void* d_ws, size_t ws_size,
                              hipStream_t stream)
{
    const float* hid = (const float*)d_in[0];
    const float* qw  = (const float*)d_in[1];
    const float* qb  = (const float*)d_in[2];
    const float* kw  = (const float*)d_in[3];
    const float* qnw = (const float*)d_in[4];
    const float* knw = (const float*)d_in[5];
    const float* kb  = (const float*)d_in[6];
    const float* bb  = (const float*)d_in[7];
    float* out = (float*)d_out;

    u16* Wst = (u16*)d_ws;                                        // 5,242,880 B
    u16* P0  = (u16*)((char*)d_ws + (size_t)NCOL * KD * 2);       // 20,971,520 B
    u16* P1  = P0 + (size_t)NSEQ * NCOL;                          // 20,971,520 B

    wconv_kernel<<<WCONV_THREADS / 256, 256, 0, stream>>>(qw, kw, Wst);
    gemm_kernel<<<256, 512, 0, stream>>>(hid, Wst, P0, P1);
    gate_kernel<<<NSEQ * 32 / 256, 256, 0, stream>>>(P0, P1, qb, qnw, knw, kb, bb, out);
}